// Round 11
// baseline (689.618 us; speedup 1.0000x reference)
//
#include <hip/hip_runtime.h>
#include <hip/hip_bf16.h>

// MoE expert MLP: y[b] = (gelu(x[b] @ W1[e] + b1[e]) @ W2[e] + b2[e]) * w[b]
// B=8, S=4096, D=1024, F=4096, E=8. f32 in/out; bf16 MFMA 16x16x32, 256^2 tile.
// R11 = R10 + panel-persistent blocks for g1: each block loops PN=4 column
// panels with the staging pipeline flowing across panel boundaries, so g1
// gets g2's shape (256 blocks, 64 effective K-tiles per block).

#define B_ 8
#define S_ 4096
#define D_ 1024
#define F_ 4096
#define E_ 8

typedef __bf16 bf16x8 __attribute__((ext_vector_type(8)));
typedef float f32x4 __attribute__((ext_vector_type(4)));

__device__ __forceinline__ unsigned short f2bf(float f) {
  unsigned u = __float_as_uint(f);
  u += 0x7FFFu + ((u >> 16) & 1u);   // round-to-nearest-even
  return (unsigned short)(u >> 16);
}

#define GLD16(g, l) __builtin_amdgcn_global_load_lds(                         \
    (const __attribute__((address_space(1))) unsigned int*)(g),              \
    (__attribute__((address_space(3))) unsigned int*)(l), 16, 0, 0)

// ---------------------------------------------------------------------------
// Transpose + f32->bf16:  src (nmat, R, C) f32  ->  dst (nmat, C, R) bf16
// ---------------------------------------------------------------------------
__global__ __launch_bounds__(256) void transpose_cvt_kernel(
    const float* __restrict__ src, unsigned short* __restrict__ dst,
    int R, int C) {
  __shared__ float t[32][33];
  const float* s = src + (size_t)blockIdx.z * R * C;
  unsigned short* d = dst + (size_t)blockIdx.z * R * C;
  int c0 = blockIdx.x * 32, r0 = blockIdx.y * 32;
  int x = threadIdx.x, y = threadIdx.y;      // 32 x 8
#pragma unroll
  for (int j = 0; j < 32; j += 8)
    t[y + j][x] = s[(size_t)(r0 + y + j) * C + (c0 + x)];
  __syncthreads();
#pragma unroll
  for (int j = 0; j < 32; j += 8)
    d[(size_t)(c0 + y + j) * R + (r0 + x)] = f2bf(t[x][y + j]);
}

// ---------------------------------------------------------------------------
// f32 -> bf16 flat convert, vectorized
// ---------------------------------------------------------------------------
__global__ __launch_bounds__(256) void cvt_bf16_kernel(
    const float* __restrict__ src, unsigned short* __restrict__ dst, long n4) {
  long i = (long)blockIdx.x * 256 + threadIdx.x;
  long stride = (long)gridDim.x * 256;
  for (; i < n4; i += stride) {
    float4 v = ((const float4*)src)[i];
    uint2 o;
    o.x = (unsigned)f2bf(v.x) | ((unsigned)f2bf(v.y) << 16);
    o.y = (unsigned)f2bf(v.z) | ((unsigned)f2bf(v.w) << 16);
    ((uint2*)dst)[i] = o;
  }
}

// ---------------------------------------------------------------------------
// 256x256-tile 4-phase GEMM (R5 schedule; R10 column map; R11 panel loop).
//   8 waves (2M x 4N); wave owns one contiguous 64-col stripe.
//   Global tile id g in [0, PN*NT): panel p = g>>LOGNT, k-tile tt = g&(NT-1).
//   A k-offset wraps per panel; B pointer advances by 256*LDK per panel.
//   Staging pipeline (Ah1@ph1 of g+1; Ah0/Bh0/Bh1@ph2-4 of g+2; vmcnt(6)
//   at ph4 only) flows uninterrupted across panel boundaries.
//   Per-panel epilogue runs between tile barriers (global stores only; LDS
//   untouched; staging loads stay in flight).
// ---------------------------------------------------------------------------

#define STAGE_A(cur, h, g)                                                    \
  {                                                                           \
    const unsigned short* g0_ = Abase + (size_t)((h) * 128 + sr) * LDK +      \
                                ((g) & (NT - 1)) * 64 + sgc * 8;              \
    GLD16(g0_, smem + (cur) * 65536 + (h) * 16384 + wave * 1024);             \
    GLD16(g0_ + (size_t)64 * LDK,                                             \
          smem + (cur) * 65536 + (h) * 16384 + 8192 + wave * 1024);           \
  }

#define STAGE_B(cur, h, g)                                                    \
  {                                                                           \
    const unsigned short* g0_ = Bbase +                                       \
                                (size_t)((g) >> LOGNT) * 256 * LDK +          \
                                (size_t)((h) * 128 + sr) * LDK +              \
                                ((g) & (NT - 1)) * 64 + sgc * 8;              \
    GLD16(g0_, smem + (cur) * 65536 + 32768 + (h) * 16384 + wave * 1024);     \
    GLD16(g0_ + (size_t)64 * LDK,                                             \
          smem + (cur) * 65536 + 32768 + (h) * 16384 + 8192 + wave * 1024);   \
  }

#define LDA_HALF(cur, H)                                                      \
  _Pragma("unroll") for (int m = 0; m < 4; ++m) {                             \
    const char* p_ = smem + (cur) * 65536 + (H) * 16384 +                     \
                     (wr * 64 + m * 16 + l15) * 128;                          \
    aM[m][0] = *(const bf16x8*)(p_ + ca0);                                    \
    aM[m][1] = *(const bf16x8*)(p_ + ca1);                                    \
  }

// B-frags: rows (wc&1)*64 + (Q*2+n)*16 + l15 of half (wc>>1)
#define LDB_Q(cur, Q, breg)                                                   \
  _Pragma("unroll") for (int n = 0; n < 2; ++n) {                             \
    const char* p_ = smem + (cur) * 65536 + 32768 + (wc >> 1) * 16384 +       \
                     ((wc & 1) * 64 + ((Q) * 2 + n) * 16 + l15) * 128;        \
    breg[n][0] = *(const bf16x8*)(p_ + ca0);                                  \
    breg[n][1] = *(const bf16x8*)(p_ + ca1);                                  \
  }

#define MMA_Q(MB, breg, NB)                                                   \
  _Pragma("unroll") for (int ks = 0; ks < 2; ++ks)                            \
      _Pragma("unroll") for (int m = 0; m < 4; ++m)                           \
          _Pragma("unroll") for (int n = 0; n < 2; ++n)                       \
              acc[(MB) + m][(NB) + n] =                                       \
      __builtin_amdgcn_mfma_f32_16x16x32_bf16(                                \
          aM[m][ks], breg[n][ks], acc[(MB) + m][(NB) + n], 0, 0, 0);

#define PH_END                                                                \
  __builtin_amdgcn_s_setprio(0);                                              \
  __builtin_amdgcn_sched_barrier(0);                                          \
  __builtin_amdgcn_s_barrier();

// MODE: 2 = full staging, 1 = tail-1 (stage Ah1 of g+1 only, drain), 0 = last
#define TILE(cur, g, MODE)                                                    \
  LDA_HALF(cur, 0);                                                           \
  LDB_Q(cur, 0, bq0);                                                         \
  if ((MODE) >= 1) STAGE_A((cur) ^ 1, 1, (g) + 1);                            \
  __builtin_amdgcn_s_setprio(1);                                              \
  MMA_Q(0, bq0, 0);                                                           \
  PH_END;                                                                     \
  LDB_Q(cur, 1, bq1);                                                         \
  if ((MODE) == 2) STAGE_A(cur, 0, (g) + 2);                                  \
  __builtin_amdgcn_s_setprio(1);                                              \
  MMA_Q(0, bq1, 2);                                                           \
  PH_END;                                                                     \
  LDA_HALF(cur, 1);                                                           \
  if ((MODE) == 2) STAGE_B(cur, 0, (g) + 2);                                  \
  __builtin_amdgcn_s_setprio(1);                                              \
  MMA_Q(4, bq0, 0);                                                           \
  PH_END;                                                                     \
  if ((MODE) == 2) STAGE_B(cur, 1, (g) + 2);                                  \
  __builtin_amdgcn_s_setprio(1);                                              \
  MMA_Q(4, bq1, 2);                                                           \
  __builtin_amdgcn_s_setprio(0);                                              \
  __builtin_amdgcn_sched_barrier(0);                                          \
  if ((MODE) == 2) asm volatile("s_waitcnt vmcnt(6)" ::: "memory");           \
  if ((MODE) == 1) asm volatile("s_waitcnt vmcnt(0)" ::: "memory");           \
  __builtin_amdgcn_s_barrier();

// per-panel epilogue: bias + (gelu|scale), full-128B-line stores, acc reset
#define WRITEPANEL(p)                                                         \
  {                                                                           \
    const int colbase =                                                       \
        (bn0 + (p)) * 256 + (wc >> 1) * 128 + (wc & 1) * 64 + l15;            \
    float bv[4];                                                              \
    _Pragma("unroll") for (int n = 0; n < 4; ++n)                             \
        bv[n] = bias[(size_t)e * NCOL + colbase + n * 16];                    \
    _Pragma("unroll") for (int m = 0; m < 8; ++m) {                           \
      const int trow =                                                        \
          (m < 4 ? wr * 64 + m * 16 : 128 + wr * 64 + (m - 4) * 16) +         \
          lhi * 4;                                                            \
      const size_t rowb = (size_t)bm * 256 + trow;                            \
      _Pragma("unroll") for (int r = 0; r < 4; ++r) {                         \
        const size_t off = (rowb + r) * NCOL + colbase;                       \
        if (GELU) {                                                           \
          _Pragma("unroll") for (int n = 0; n < 4; ++n) {                     \
            float v = acc[m][n][r] + bv[n];                                   \
            float zz = v * (0.79788456080286536f + 0.0356774081f * v * v);    \
            float gg = v / (1.0f + __expf(-2.0f * zz));                       \
            ((unsigned short*)Out)[off + n * 16] = f2bf(gg);                  \
          }                                                                   \
        } else {                                                              \
          _Pragma("unroll") for (int n = 0; n < 4; ++n)                       \
              ((float*)Out)[off + n * 16] = (acc[m][n][r] + bv[n]) * scale;   \
        }                                                                     \
      }                                                                       \
    }                                                                         \
    _Pragma("unroll") for (int m = 0; m < 8; ++m)                             \
        _Pragma("unroll") for (int n = 0; n < 4; ++n)                         \
            acc[m][n] = (f32x4){0.f, 0.f, 0.f, 0.f};                          \
  }

template <int NT, int LOGNT, int PN, int LDK, int NCOL, bool GELU>
__global__ __launch_bounds__(512, 2) void gemm8p_kernel(
    const unsigned short* __restrict__ A,   // [rows][LDK] bf16 (chunk-local)
    const unsigned short* __restrict__ Bw,  // [E][NCOL][LDK] bf16
    const float* __restrict__ bias,         // [E][NCOL]
    const int* __restrict__ eidx, const float* __restrict__ ew,
    void* __restrict__ Out, int grow0, int nbm) {
  extern __shared__ __align__(16) char smem[];
  constexpr int TOT = NT * PN;

  const int tid = threadIdx.x;
  const int lane = tid & 63;
  const int wave = tid >> 6;
  const int wr = wave >> 2;         // 0..1 (M)
  const int wc = wave & 3;          // 0..3 (N stripe)
  const int l15 = lane & 15, lhi = lane >> 4;

  const int nwg = nbm * (NCOL / 256 / PN);
  int wg = blockIdx.x;
  if ((nwg & 7) == 0) wg = (wg & 7) * (nwg >> 3) + (wg >> 3);  // XCD swizzle
  const int bm = wg % nbm;
  const int bn0 = (wg / nbm) * PN;

  const int bat = (grow0 + bm * 256) >> 12;
  const int e = eidx[bat];

  const unsigned short* Abase = A + (size_t)bm * 256 * LDK;
  const unsigned short* Bbase =
      Bw + (size_t)e * NCOL * LDK + (size_t)bn0 * 256 * LDK;

  // staging per-thread constants (swizzled source)
  const int sr = tid >> 3;                  // 0..63 (row within 64-row slab)
  const int sgc = (tid & 7) ^ (sr & 7);     // global 16B chunk for lds chunk
  // ds_read per-thread swizzled chunk offsets (row&7 == l15&7 always)
  const int ca0 = ((lhi ^ (l15 & 7)) << 4);
  const int ca1 = (((4 + lhi) ^ (l15 & 7)) << 4);

  f32x4 acc[8][4] = {};
  bf16x8 aM[4][2], bq0[2][2], bq1[2][2];
  const float scale = GELU ? 1.0f : ew[bat];

  // prologue: tile0 all 4 halves, tile1 first 3 (Ah0,Bh0,Bh1)
  STAGE_A(0, 0, 0);
  STAGE_B(0, 0, 0);
  STAGE_B(0, 1, 0);
  STAGE_A(0, 1, 0);
  STAGE_A(1, 0, 1);
  STAGE_B(1, 0, 1);
  STAGE_B(1, 1, 1);
  asm volatile("s_waitcnt vmcnt(6)" ::: "memory");
  __builtin_amdgcn_s_barrier();

#pragma unroll 1
  for (int g = 0; g < TOT - 2; g += 2) {
    TILE(0, g, 2);
    TILE(1, g + 1, 2);
    if (PN > 1 && ((g + 1) & (NT - 1)) == (NT - 1)) {
      WRITEPANEL((g + 1) >> LOGNT);
    }
  }
  TILE(0, TOT - 2, 1);
  TILE(1, TOT - 1, 0);
  WRITEPANEL(PN - 1);
}

// ---------------------------------------------------------------------------
extern "C" void kernel_launch(void* const* d_in, const int* in_sizes, int n_in,
                              void* d_out, int out_size, void* d_ws,
                              size_t ws_size, hipStream_t stream) {
  const float* x = (const float*)d_in[0];
  const float* ew = (const float*)d_in[1];
  const float* W1 = (const float*)d_in[2];
  const float* b1 = (const float*)d_in[3];
  const float* W2 = (const float*)d_in[4];
  const float* b2 = (const float*)d_in[5];
  const int* eidx = (const int*)d_in[6];
  float* out = (float*)d_out;

  char* ws = (char*)d_ws;
  const size_t WT = (size_t)E_ * F_ * D_ * 2;  // 64 MiB per transposed weight
  const size_t XB = (size_t)B_ * S_ * D_ * 2;  // 64 MiB bf16 x
  unsigned short* w1t = (unsigned short*)ws;
  unsigned short* w2t = (unsigned short*)(ws + WT);

  // g1: NT=16 (K=1024), PN=4 panels over F; g2: NT=64 (K=4096), PN=1 over D.
  auto g1 = gemm8p_kernel<16, 4, 4, D_, F_, true>;
  auto g2 = gemm8p_kernel<64, 6, 1, F_, D_, false>;
  hipFuncSetAttribute((const void*)g1,
                      hipFuncAttributeMaxDynamicSharedMemorySize, 131072);
  hipFuncSetAttribute((const void*)g2,
                      hipFuncAttributeMaxDynamicSharedMemorySize, 131072);

  // weights: W1 (E,D,F)->(E,F,D), W2 (E,F,D)->(E,D,F), bf16
  transpose_cvt_kernel<<<dim3(F_ / 32, D_ / 32, E_), dim3(32, 8), 0, stream>>>(
      W1, w1t, D_, F_);
  transpose_cvt_kernel<<<dim3(D_ / 32, F_ / 32, E_), dim3(32, 8), 0, stream>>>(
      W2, w2t, F_, D_);

  const long total_rows = (long)B_ * S_;  // 32768

  // full xbf + hbuf chunked at <=16384 rows so H stays L3-resident
  long avail = (long)ws_size - (long)(2 * WT + XB);
  long CH = avail > 0 ? (avail / ((long)F_ * 2)) : 0;
  CH = (CH / 256) * 256;
  if (CH > 16384) CH = 16384;
  if (CH > total_rows) CH = total_rows;

  if (CH >= 256) {
    unsigned short* xbf = (unsigned short*)(ws + 2 * WT);
    unsigned short* hbuf = (unsigned short*)(ws + 2 * WT + XB);
    cvt_bf16_kernel<<<2048, 256, 0, stream>>>(x, xbf, (long)B_ * S_ * D_ / 4);
    for (long r0 = 0; r0 < total_rows; r0 += CH) {
      long nr = total_rows - r0;
      if (nr > CH) nr = CH;
      int nbm = (int)(nr / 256);
      g1<<<dim3(nbm * (F_ / 256 / 4)), 512, 131072, stream>>>(
          xbf + r0 * D_, w1t, b1, eidx, ew, hbuf, (int)r0, nbm);
      g2<<<dim3(nbm * (D_ / 256)), 512, 131072, stream>>>(
          hbuf, w2t, b2, eidx, ew, out + r0 * D_, (int)r0, nbm);
    }
  } else {
    // tiny-ws fallback: chunk xbf and hbuf together
    long cap = ((long)ws_size - (long)(2 * WT)) / ((long)(D_ + F_) * 2);
    long chunk = (cap / 256) * 256;
    if (chunk > total_rows) chunk = total_rows;
    if (chunk < 256) chunk = 256;
    unsigned short* xbf = (unsigned short*)(ws + 2 * WT);
    unsigned short* hbuf = xbf + (size_t)chunk * D_;
    for (long r0 = 0; r0 < total_rows; r0 += chunk) {
      long nr = total_rows - r0;
      if (nr > chunk) nr = chunk;
      cvt_bf16_kernel<<<512, 256, 0, stream>>>(x + r0 * D_, xbf, nr * D_ / 4);
      int nbm = (int)(nr / 256);
      g1<<<dim3(nbm * (F_ / 256 / 4)), 512, 131072, stream>>>(
          xbf, w1t, b1, eidx, ew, hbuf, (int)r0, nbm);
      g2<<<dim3(nbm * (D_ / 256)), 512, 131072, stream>>>(
          hbuf, w2t, b2, eidx, ew, out + r0 * D_, (int)r0, nbm);
    }
  }
}

// Round 12
// 646.423 us; speedup vs baseline: 1.0668x; 1.0668x over previous
//
#include <hip/hip_runtime.h>
#include <hip/hip_bf16.h>

// MoE expert MLP: y[b] = (gelu(x[b] @ W1[e] + b1[e]) @ W2[e] + b2[e]) * w[b]
// B=8, S=4096, D=1024, F=4096, E=8. f32 in/out; bf16 MFMA 16x16x32, 256^2 tile.
// R12 = R10 (best measured: 663 us) + expert-gated weight transposes (skip
// experts not present in expert_indices; expected ~5.2/8 used).

#define B_ 8
#define S_ 4096
#define D_ 1024
#define F_ 4096
#define E_ 8

typedef __bf16 bf16x8 __attribute__((ext_vector_type(8)));
typedef float f32x4 __attribute__((ext_vector_type(4)));

__device__ __forceinline__ unsigned short f2bf(float f) {
  unsigned u = __float_as_uint(f);
  u += 0x7FFFu + ((u >> 16) & 1u);   // round-to-nearest-even
  return (unsigned short)(u >> 16);
}

#define GLD16(g, l) __builtin_amdgcn_global_load_lds(                         \
    (const __attribute__((address_space(1))) unsigned int*)(g),              \
    (__attribute__((address_space(3))) unsigned int*)(l), 16, 0, 0)

// ---------------------------------------------------------------------------
// Transpose + f32->bf16:  src (nmat, R, C) f32  ->  dst (nmat, C, R) bf16
// Gated: blocks for experts not in eidx[0..B_) exit immediately (their
// output region is never read by the GEMMs).
// ---------------------------------------------------------------------------
__global__ __launch_bounds__(256) void transpose_cvt_kernel(
    const float* __restrict__ src, unsigned short* __restrict__ dst,
    int R, int C, const int* __restrict__ eidx) {
  bool used = false;
#pragma unroll
  for (int i = 0; i < B_; ++i) used |= (eidx[i] == (int)blockIdx.z);
  if (!used) return;

  __shared__ float t[32][33];
  const float* s = src + (size_t)blockIdx.z * R * C;
  unsigned short* d = dst + (size_t)blockIdx.z * R * C;
  int c0 = blockIdx.x * 32, r0 = blockIdx.y * 32;
  int x = threadIdx.x, y = threadIdx.y;      // 32 x 8
#pragma unroll
  for (int j = 0; j < 32; j += 8)
    t[y + j][x] = s[(size_t)(r0 + y + j) * C + (c0 + x)];
  __syncthreads();
#pragma unroll
  for (int j = 0; j < 32; j += 8)
    d[(size_t)(c0 + y + j) * R + (r0 + x)] = f2bf(t[x][y + j]);
}

// ---------------------------------------------------------------------------
// f32 -> bf16 flat convert, vectorized
// ---------------------------------------------------------------------------
__global__ __launch_bounds__(256) void cvt_bf16_kernel(
    const float* __restrict__ src, unsigned short* __restrict__ dst, long n4) {
  long i = (long)blockIdx.x * 256 + threadIdx.x;
  long stride = (long)gridDim.x * 256;
  for (; i < n4; i += stride) {
    float4 v = ((const float4*)src)[i];
    uint2 o;
    o.x = (unsigned)f2bf(v.x) | ((unsigned)f2bf(v.y) << 16);
    o.y = (unsigned)f2bf(v.z) | ((unsigned)f2bf(v.w) << 16);
    ((uint2*)dst)[i] = o;
  }
}

// ---------------------------------------------------------------------------
// 256x256-tile 4-phase GEMM (R5 schedule; R10 column mapping). Best measured.
//   8 waves (2M x 4N): wave owns one contiguous 64-col stripe:
//   col = (wc>>1)*128 + (wc&1)*64 + n*16 + l15 — B-frags from one B-half.
//   LDS 128 KiB: buf{0,1} x { A[2 halves 128x64] , B[2 halves 128x64] },
//   16B-chunk XOR swizzle: chunk cc of row r holds global k-chunk cc^(r&7)
//   (0 bank conflicts at this read pattern, verified R5/R10).
//   Stages per tile t: ph1 Ah1(t+1)->buf^1, ph2 Ah0(t+2), ph3 Bh0(t+2),
//   ph4 Bh1(t+2); vmcnt(6) only at ph4 (3 half-tiles in flight).
//   Epilogue: per (m,r) four consecutive n-stores cover one full 128B line
//   (bf16) / two lines (f32) -> no RMW, no LDS roundtrip.
// ---------------------------------------------------------------------------

#define STAGE(cur, op, h, tk, base)                                           \
  {                                                                           \
    const unsigned short* g0_ = (base) + (size_t)((h) * 128 + sr) * LDK +     \
                                (tk) * 64 + sgc * 8;                          \
    GLD16(g0_, smem + (cur) * 65536 + (op) * 32768 + (h) * 16384 +            \
                   wave * 1024);                                              \
    GLD16(g0_ + (size_t)64 * LDK,                                             \
          smem + (cur) * 65536 + (op) * 32768 + (h) * 16384 + 8192 +          \
              wave * 1024);                                                   \
  }

#define LDA_HALF(cur, H)                                                      \
  _Pragma("unroll") for (int m = 0; m < 4; ++m) {                             \
    const char* p_ = smem + (cur) * 65536 + (H) * 16384 +                     \
                     (wr * 64 + m * 16 + l15) * 128;                          \
    aM[m][0] = *(const bf16x8*)(p_ + ca0);                                    \
    aM[m][1] = *(const bf16x8*)(p_ + ca1);                                    \
  }

// B-frags: rows (wc&1)*64 + (Q*2+n)*16 + l15 of half (wc>>1)
#define LDB_Q(cur, Q, breg)                                                   \
  _Pragma("unroll") for (int n = 0; n < 2; ++n) {                             \
    const char* p_ = smem + (cur) * 65536 + 32768 + (wc >> 1) * 16384 +       \
                     ((wc & 1) * 64 + ((Q) * 2 + n) * 16 + l15) * 128;        \
    breg[n][0] = *(const bf16x8*)(p_ + ca0);                                  \
    breg[n][1] = *(const bf16x8*)(p_ + ca1);                                  \
  }

#define MMA_Q(MB, breg, NB)                                                   \
  _Pragma("unroll") for (int ks = 0; ks < 2; ++ks)                            \
      _Pragma("unroll") for (int m = 0; m < 4; ++m)                           \
          _Pragma("unroll") for (int n = 0; n < 2; ++n)                       \
              acc[(MB) + m][(NB) + n] =                                       \
      __builtin_amdgcn_mfma_f32_16x16x32_bf16(                                \
          aM[m][ks], breg[n][ks], acc[(MB) + m][(NB) + n], 0, 0, 0);

#define PH_END                                                                \
  __builtin_amdgcn_s_setprio(0);                                              \
  __builtin_amdgcn_sched_barrier(0);                                          \
  __builtin_amdgcn_s_barrier();

// MODE: 2 = full staging, 1 = tail-1 (stage Ah1 only, drain), 0 = last tile
#define TILE(cur, t, MODE)                                                    \
  LDA_HALF(cur, 0);                                                           \
  LDB_Q(cur, 0, bq0);                                                         \
  if ((MODE) >= 1) STAGE((cur) ^ 1, 0, 1, (t) + 1, Abase);                    \
  __builtin_amdgcn_s_setprio(1);                                              \
  MMA_Q(0, bq0, 0);                                                           \
  PH_END;                                                                     \
  LDB_Q(cur, 1, bq1);                                                         \
  if ((MODE) == 2) STAGE(cur, 0, 0, (t) + 2, Abase);                          \
  __builtin_amdgcn_s_setprio(1);                                              \
  MMA_Q(0, bq1, 2);                                                           \
  PH_END;                                                                     \
  LDA_HALF(cur, 1);                                                           \
  if ((MODE) == 2) STAGE(cur, 1, 0, (t) + 2, Bbase);                          \
  __builtin_amdgcn_s_setprio(1);                                              \
  MMA_Q(4, bq0, 0);                                                           \
  PH_END;                                                                     \
  if ((MODE) == 2) STAGE(cur, 1, 1, (t) + 2, Bbase);                          \
  __builtin_amdgcn_s_setprio(1);                                              \
  MMA_Q(4, bq1, 2);                                                           \
  __builtin_amdgcn_s_setprio(0);                                              \
  __builtin_amdgcn_sched_barrier(0);                                          \
  if ((MODE) == 2) asm volatile("s_waitcnt vmcnt(6)" ::: "memory");           \
  if ((MODE) == 1) asm volatile("s_waitcnt vmcnt(0)" ::: "memory");           \
  __builtin_amdgcn_s_barrier();

template <int NT, int LDK, int NCOL, bool GELU>
__global__ __launch_bounds__(512, 2) void gemm8p_kernel(
    const unsigned short* __restrict__ A,   // [rows][LDK] bf16 (chunk-local)
    const unsigned short* __restrict__ Bw,  // [E][NCOL][LDK] bf16
    const float* __restrict__ bias,         // [E][NCOL]
    const int* __restrict__ eidx, const float* __restrict__ ew,
    void* __restrict__ Out, int grow0, int nbm) {
  extern __shared__ __align__(16) char smem[];

  const int tid = threadIdx.x;
  const int lane = tid & 63;
  const int wave = tid >> 6;
  const int wr = wave >> 2;         // 0..1 (M)
  const int wc = wave & 3;          // 0..3 (N stripe)
  const int l15 = lane & 15, lhi = lane >> 4;

  const int nwg = nbm * (NCOL / 256);
  int wg = blockIdx.x;
  if ((nwg & 7) == 0) wg = (wg & 7) * (nwg >> 3) + (wg >> 3);  // XCD swizzle
  const int bm = wg % nbm, bn = wg / nbm;

  const int bat = (grow0 + bm * 256) >> 12;
  const int e = eidx[bat];

  const unsigned short* Abase = A + (size_t)bm * 256 * LDK;
  const unsigned short* Bbase =
      Bw + (size_t)e * (F_ * D_) + (size_t)bn * 256 * LDK;

  // staging per-thread constants (swizzled source)
  const int sr = tid >> 3;                  // 0..63 (row within 64-row slab)
  const int sgc = (tid & 7) ^ (sr & 7);     // global 16B chunk for lds chunk
  // ds_read per-thread swizzled chunk offsets (row&7 == l15&7 always)
  const int ca0 = ((lhi ^ (l15 & 7)) << 4);
  const int ca1 = (((4 + lhi) ^ (l15 & 7)) << 4);

  f32x4 acc[8][4] = {};
  bf16x8 aM[4][2], bq0[2][2], bq1[2][2];

  // prologue: tile0 all 4 halves, tile1 first 3 (Ah0,Bh0,Bh1)
  STAGE(0, 0, 0, 0, Abase);
  STAGE(0, 1, 0, 0, Bbase);
  STAGE(0, 1, 1, 0, Bbase);
  STAGE(0, 0, 1, 0, Abase);
  STAGE(1, 0, 0, 1, Abase);
  STAGE(1, 1, 0, 1, Bbase);
  STAGE(1, 1, 1, 1, Bbase);
  asm volatile("s_waitcnt vmcnt(6)" ::: "memory");
  __builtin_amdgcn_s_barrier();

#pragma unroll 1
  for (int t = 0; t < NT - 2; t += 2) {
    TILE(0, t, 2);
    TILE(1, t + 1, 2);
  }
  TILE(0, NT - 2, 1);
  TILE(1, NT - 1, 0);

  // ---- direct epilogue: wave owns 64 contiguous cols; per (m,r) the four
  // n-stores are back-to-back on one 128B line (bf16) / two lines (f32) ----
  const int colbase = bn * 256 + (wc >> 1) * 128 + (wc & 1) * 64 + l15;
  float bv[4];
#pragma unroll
  for (int n = 0; n < 4; ++n) bv[n] = bias[(size_t)e * NCOL + colbase + n * 16];
  const float scale = GELU ? 1.0f : ew[bat];

#pragma unroll
  for (int m = 0; m < 8; ++m) {
    const int trow =
        (m < 4 ? wr * 64 + m * 16 : 128 + wr * 64 + (m - 4) * 16) + lhi * 4;
    const size_t rowb = (size_t)bm * 256 + trow;
#pragma unroll
    for (int r = 0; r < 4; ++r) {
      const size_t off = (rowb + r) * NCOL + colbase;
      if (GELU) {
#pragma unroll
        for (int n = 0; n < 4; ++n) {
          float v = acc[m][n][r] + bv[n];
          // tanh-form gelu: v * sigmoid(2 * 0.79788456*(v + 0.044715 v^3))
          float zz = v * (0.79788456080286536f + 0.0356774081f * v * v);
          float g = v / (1.0f + __expf(-2.0f * zz));
          ((unsigned short*)Out)[off + n * 16] = f2bf(g);
        }
      } else {
#pragma unroll
        for (int n = 0; n < 4; ++n)
          ((float*)Out)[off + n * 16] = (acc[m][n][r] + bv[n]) * scale;
      }
    }
  }
}

// ---------------------------------------------------------------------------
extern "C" void kernel_launch(void* const* d_in, const int* in_sizes, int n_in,
                              void* d_out, int out_size, void* d_ws,
                              size_t ws_size, hipStream_t stream) {
  const float* x = (const float*)d_in[0];
  const float* ew = (const float*)d_in[1];
  const float* W1 = (const float*)d_in[2];
  const float* b1 = (const float*)d_in[3];
  const float* W2 = (const float*)d_in[4];
  const float* b2 = (const float*)d_in[5];
  const int* eidx = (const int*)d_in[6];
  float* out = (float*)d_out;

  char* ws = (char*)d_ws;
  const size_t WT = (size_t)E_ * F_ * D_ * 2;  // 64 MiB per transposed weight
  const size_t XB = (size_t)B_ * S_ * D_ * 2;  // 64 MiB bf16 x
  unsigned short* w1t = (unsigned short*)ws;
  unsigned short* w2t = (unsigned short*)(ws + WT);

  auto g1 = gemm8p_kernel<16, D_, F_, true>;
  auto g2 = gemm8p_kernel<64, F_, D_, false>;
  hipFuncSetAttribute((const void*)g1,
                      hipFuncAttributeMaxDynamicSharedMemorySize, 131072);
  hipFuncSetAttribute((const void*)g2,
                      hipFuncAttributeMaxDynamicSharedMemorySize, 131072);

  // weights (used experts only): W1 (E,D,F)->(E,F,D), W2 (E,F,D)->(E,D,F)
  transpose_cvt_kernel<<<dim3(F_ / 32, D_ / 32, E_), dim3(32, 8), 0, stream>>>(
      W1, w1t, D_, F_, eidx);
  transpose_cvt_kernel<<<dim3(D_ / 32, F_ / 32, E_), dim3(32, 8), 0, stream>>>(
      W2, w2t, F_, D_, eidx);

  const long total_rows = (long)B_ * S_;  // 32768

  // full xbf + hbuf chunked at <=16384 rows so H stays L3-resident
  long avail = (long)ws_size - (long)(2 * WT + XB);
  long CH = avail > 0 ? (avail / ((long)F_ * 2)) : 0;
  CH = (CH / 256) * 256;
  if (CH > 16384) CH = 16384;
  if (CH > total_rows) CH = total_rows;

  if (CH >= 256) {
    unsigned short* xbf = (unsigned short*)(ws + 2 * WT);
    unsigned short* hbuf = (unsigned short*)(ws + 2 * WT + XB);
    cvt_bf16_kernel<<<2048, 256, 0, stream>>>(x, xbf, (long)B_ * S_ * D_ / 4);
    for (long r0 = 0; r0 < total_rows; r0 += CH) {
      long nr = total_rows - r0;
      if (nr > CH) nr = CH;
      int nbm = (int)(nr / 256);
      g1<<<dim3(nbm * (F_ / 256)), 512, 131072, stream>>>(
          xbf + r0 * D_, w1t, b1, eidx, ew, hbuf, (int)r0, nbm);
      g2<<<dim3(nbm * (D_ / 256)), 512, 131072, stream>>>(
          hbuf, w2t, b2, eidx, ew, out + r0 * D_, (int)r0, nbm);
    }
  } else {
    // tiny-ws fallback: chunk xbf and hbuf together
    long cap = ((long)ws_size - (long)(2 * WT)) / ((long)(D_ + F_) * 2);
    long chunk = (cap / 256) * 256;
    if (chunk > total_rows) chunk = total_rows;
    if (chunk < 256) chunk = 256;
    unsigned short* xbf = (unsigned short*)(ws + 2 * WT);
    unsigned short* hbuf = xbf + (size_t)chunk * D_;
    for (long r0 = 0; r0 < total_rows; r0 += chunk) {
      long nr = total_rows - r0;
      if (nr > chunk) nr = chunk;
      cvt_bf16_kernel<<<512, 256, 0, stream>>>(x + r0 * D_, xbf, nr * D_ / 4);
      int nbm = (int)(nr / 256);
      g1<<<dim3(nbm * (F_ / 256)), 512, 131072, stream>>>(
          xbf, w1t, b1, eidx, ew, hbuf, (int)r0, nbm);
      g2<<<dim3(nbm * (D_ / 256)), 512, 131072, stream>>>(
          hbuf, w2t, b2, eidx, ew, out + r0 * D_, (int)r0, nbm);
    }
  }
}